// Round 5
// baseline (750.746 us; speedup 1.0000x reference)
//
#include <hip/hip_runtime.h>
#include <hip/hip_bf16.h>
#include <stdint.h>

typedef __attribute__((ext_vector_type(4))) float f32x4;
typedef __attribute__((ext_vector_type(16))) float f32x16;
typedef __attribute__((ext_vector_type(8))) short bf16x8;

__device__ __forceinline__ unsigned short f2bf(float f) {
    __hip_bfloat16 h = __float2bfloat16(f);
    return *reinterpret_cast<unsigned short*>(&h);
}

__device__ __forceinline__ void gload_lds16(const void* g, void* l) {
    __builtin_amdgcn_global_load_lds(
        (const __attribute__((address_space(1))) void*)g,
        (__attribute__((address_space(3))) void*)l, 16, 0, 0);
}

// Logical-tile -> (m0,n0): XCD round-robin with n-major order inside each
// XCD's contiguous chunk (R1 L2-locality fix, verified: FETCH 1.56->0.56GB).
__device__ __forceinline__ void tile_map(int logical, int nlog, int nbx,
                                         int& m0, int& n0)
{
    const int per = nlog >> 3;
    const int xcd = logical & 7;
    const int l   = logical >> 3;
    const int mrows = per / nbx;
    if (mrows * nbx == per) {
        const int nj = l / mrows;
        const int mi = l - nj * mrows;
        m0 = (xcd * mrows + mi) * 256;
        n0 = nj * 256;
    } else {
        const int wg = xcd * per + l;
        m0 = (wg / nbx) * 256;
        n0 = (wg % nbx) * 256;
    }
}

// ---------------------------------------------------------------------------
// Prep A: convert x f32 -> bf16 (memory-bound single pass).
// ---------------------------------------------------------------------------
__global__ __launch_bounds__(256)
void wq_cvt(const float* __restrict__ x, unsigned short* __restrict__ xb)
{
    const size_t i = (size_t)blockIdx.x * 256 + threadIdx.x;   // 8 elems/thread
    const f32x4 lo = ((const f32x4*)x)[2 * i];
    const f32x4 hi = ((const f32x4*)x)[2 * i + 1];
    union { bf16x8 v; unsigned short u[8]; } pk;
#pragma unroll
    for (int e = 0; e < 4; ++e) {
        pk.u[e]     = f2bf(lo[e]);
        pk.u[e + 4] = f2bf(hi[e]);
    }
    ((bf16x8*)xb)[i] = pk.v;
}

// ---------------------------------------------------------------------------
// Prep B: dequantize AWQ int4 -> Wt[N][K] bf16 (transposed).
// inv = [0,4,1,5,2,6,3,7] => shift = 4*((j>>1) + 4*(j&1)).
// ---------------------------------------------------------------------------
__global__ __launch_bounds__(256)
void wq_dequant(const int* __restrict__ qweight, const int* __restrict__ qzeros,
                const float* __restrict__ scales,
                unsigned short* __restrict__ Wt,
                int K, int NP, int G, int N)
{
    const int k  = blockIdx.x * 256 + threadIdx.x;
    const int np = blockIdx.y;
    const int g  = k / G;
    const int p  = qweight[(size_t)k * NP + np];
    const int zp = qzeros[(size_t)g * NP + np];
    const float* sc = scales + (size_t)g * N + (size_t)np * 8;
#pragma unroll
    for (int j = 0; j < 8; ++j) {
        const int sh = 4 * ((j >> 1) + ((j & 1) << 2));
        const float w = (float)(((p >> sh) & 0xF) - ((zp >> sh) & 0xF)) * sc[j];
        Wt[(size_t)(np * 8 + j) * K + k] = f2bf(w);
    }
}

// ---------------------------------------------------------------------------
// 256xBN 8-phase GEMM (m201 schedule), R5: 32x32x16 MFMA (2382 TF rate vs
// 2075 for 16x16x32; m06/m119).  C[M][N] = A[M][K]*Wt[N][K]^T + bias.
// 8 waves (2Mx4N), per-wave 128x(BN/4) out = acc[4 mblk][BN/128 nblk] f32x16.
// LDS unchanged: A[buf][256 rows][128B] @0, B @65536; phys granule =
// logical granule ^ (row&7) (16B granules); gload_lds linear dest +
// pre-swizzled source.  Frag layout (32x32x16): operand row = lane&31,
// k-granule = lane>>5; k-chunk c at addr base ^ (c<<5) (granule bits 4-6
// disjoint from row bits).  D: col=lane&31, row=(r&3)+8*(r>>2)+4*(lane>>5).
// Phase schedule, STAGE, vmcnt drains (p3/p7), barriers: unchanged from R3
// (R4 ping-pong reverted: measured neutral-to-negative).
// ---------------------------------------------------------------------------
template<int BN, int TMAP>
__global__ __launch_bounds__(512, 2)
void wq_gemm256(const unsigned short* __restrict__ Ah,
                const unsigned short* __restrict__ Wt,
                const float* __restrict__ bias,
                float* __restrict__ C,
                int M, int N, int K, int nbx, int n_base)
{
    constexpr int JB = BN / 128;           // 32-wide n-blocks per wave: 2 or 1
    __shared__ __align__(16) char lds[131072];

    const int tid  = threadIdx.x;
    const int lane = tid & 63;
    const int w    = tid >> 6;
    const int wr   = w >> 2;           // 0..1
    const int wc   = w & 3;            // 0..3

    int m0, n0;
    if constexpr (TMAP == 0) {
        tile_map(blockIdx.x, gridDim.x, nbx, m0, n0);
    } else {
        const int mb = M / 256;            // blocks per strip
        m0 = (blockIdx.x % mb) * 256;
        n0 = n_base + (blockIdx.x / mb) * BN;
    }

    // ---- stage addressing: wave w, issue ii covers LDS slab (ii*8+w)*1KB ----
    const int lrow = lane >> 3;                          // 0..7
    const int lcol = ((lane & 7) ^ (lrow & 7)) * 8;      // pre-swizzled src col
    const unsigned short* Asrc = Ah + (size_t)(m0 + w * 8 + lrow) * K + lcol;
    const unsigned short* Bsrc = Wt + (size_t)(n0 + w * 8 + lrow) * K + lcol;

    // ---- ds-read addressing (32x32x16 frags) ----
    const int fr32 = lane & 31;                          // operand row
    const int g32  = lane >> 5;                          // k-granule (16B)
    const int c0   = ((g32 ^ (fr32 & 7)) << 4);          // swizzled granule byte
    const int rA0  = wr * 16384 + fr32 * 128 + c0;       // m-block 0, chunk 0
    const int rB0  = 65536 + wc * (BN / 4) * 128 + fr32 * 128 + c0;

    f32x16 acc[4][JB] = {};

#define STAGE(gsrc, ob, b, h, kt)                                              \
    {                                                                          \
        _Pragma("unroll")                                                      \
        for (int ii = 0; ii < 2; ++ii)                                         \
            gload_lds16(gsrc + (size_t)((h) * 128 + ii * 64) * K + (kt),       \
                        lds + (ob) + (b) * 32768 + (h) * 16384 +               \
                            (ii * 8 + w) * 1024 + lane * 16);                  \
    }
// A frags: m-blocks {ibase, ibase+1}, k-chunks {kx/32, kx/32+1} (kx in {0,64})
#define READ_A32(dst, b, ibase, kx)                                            \
    {                                                                          \
        _Pragma("unroll")                                                      \
        for (int i = 0; i < 2; ++i)                                            \
            _Pragma("unroll")                                                  \
            for (int c = 0; c < 2; ++c)                                        \
                dst[i][c] = *(const bf16x8*)(lds + (b) * 32768 +               \
                    (((rA0 + ((ibase) + i) * 4096)) ^ ((kx) ^ (c << 5))));     \
    }
#define READ_B32(dst, b, kx)                                                   \
    {                                                                          \
        _Pragma("unroll")                                                      \
        for (int j = 0; j < JB; ++j)                                           \
            _Pragma("unroll")                                                  \
            for (int c = 0; c < 2; ++c)                                        \
                dst[j][c] = *(const bf16x8*)(lds + (b) * 32768 +               \
                    (((rB0 + j * 4096)) ^ ((kx) ^ (c << 5))));                 \
    }
#define MFMA8(ibase, af_, bf_)                                                 \
    {                                                                          \
        __builtin_amdgcn_s_setprio(1);                                         \
        _Pragma("unroll")                                                      \
        for (int i = 0; i < 2; ++i)                                            \
            _Pragma("unroll")                                                  \
            for (int j = 0; j < JB; ++j)                                       \
                _Pragma("unroll")                                              \
                for (int c = 0; c < 2; ++c)                                    \
                    acc[(ibase) + i][j] =                                      \
                        __builtin_amdgcn_mfma_f32_32x32x16_bf16(               \
                            af_[i][c], bf_[j][c], acc[(ibase) + i][j],         \
                            0, 0, 0);                                          \
        __builtin_amdgcn_s_setprio(0);                                         \
    }
#define BARF()  { __builtin_amdgcn_s_barrier(); asm volatile("" ::: "memory"); }
#define LGK0()  { asm volatile("s_waitcnt lgkmcnt(0)" ::: "memory");           \
                  __builtin_amdgcn_sched_barrier(0); }
#define VMDRAIN()                                                              \
    {                                                                          \
        if constexpr (BN == 256)                                               \
            asm volatile("s_waitcnt vmcnt(4)" ::: "memory");                   \
        else                                                                   \
            asm volatile("s_waitcnt vmcnt(2)" ::: "memory");                   \
    }

    // ---- prologue: stage tile0 (B,A) + tile1 B; drain to steady state ----
    STAGE(Bsrc, 65536, 0, 0, 0);
    if constexpr (BN == 256) STAGE(Bsrc, 65536, 0, 1, 0);
    STAGE(Asrc, 0,     0, 0, 0);
    STAGE(Asrc, 0,     0, 1, 0);
    STAGE(Bsrc, 65536, 1, 0, 64);
    if constexpr (BN == 256) STAGE(Bsrc, 65536, 1, 1, 64);
    VMDRAIN();
    BARF();

    const int nit = K / 128;
    for (int it = 0; it < nit; ++it) {
        const int kt1 = it * 128 + 64;            // tile 2it+1 A
        const int kt2 = (it * 128 + 128) % K;     // tile 2it+2
        const int kt3 = (it * 128 + 192) % K;     // tile 2it+3 B
        bf16x8 af[2][2], bf0[JB][2], bf1[JB][2];

        // ======== tile 2it (buf 0) ========
        // q0: m-blocks 0-1, k 0..31
        READ_A32(af, 0, 0, 0); READ_B32(bf0, 0, 0);
        STAGE(Asrc, 0, 1, 0, kt1);
        BARF(); LGK0();
        MFMA8(0, af, bf0);
        BARF();
        // q1: m-blocks 0-1, k 32..63
        READ_A32(af, 0, 0, 64); READ_B32(bf1, 0, 64);
        STAGE(Asrc, 0, 1, 1, kt1);
        BARF(); LGK0();
        MFMA8(0, af, bf1);
        BARF();
        // q2: m-blocks 2-3, k 0..31
        READ_A32(af, 0, 2, 0);
        STAGE(Bsrc, 65536, 0, 0, kt2);
        BARF(); LGK0();
        MFMA8(2, af, bf0);
        BARF();
        // q3: m-blocks 2-3, k 32..63
        READ_A32(af, 0, 2, 64);
        if constexpr (BN == 256) STAGE(Bsrc, 65536, 0, 1, kt2);
        BARF(); LGK0();
        MFMA8(2, af, bf1);
        VMDRAIN();
        BARF();

        // ======== tile 2it+1 (buf 1) ========
        // q4
        READ_A32(af, 1, 0, 0); READ_B32(bf0, 1, 0);
        STAGE(Asrc, 0, 0, 0, kt2);
        BARF(); LGK0();
        MFMA8(0, af, bf0);
        BARF();
        // q5
        READ_A32(af, 1, 0, 64); READ_B32(bf1, 1, 64);
        STAGE(Asrc, 0, 0, 1, kt2);
        BARF(); LGK0();
        MFMA8(0, af, bf1);
        BARF();
        // q6
        READ_A32(af, 1, 2, 0);
        STAGE(Bsrc, 65536, 1, 0, kt3);
        BARF(); LGK0();
        MFMA8(2, af, bf0);
        BARF();
        // q7
        READ_A32(af, 1, 2, 64);
        if constexpr (BN == 256) STAGE(Bsrc, 65536, 1, 1, kt3);
        BARF(); LGK0();
        MFMA8(2, af, bf1);
        VMDRAIN();
        BARF();
    }

    // ---- epilogue: 32x32 D layout: col=lane&31, row=(r&3)+8*(r>>2)+4*g32 ----
    const int crow = m0 + wr * 128;
    const int ccol = n0 + wc * (BN / 4) + fr32;
#pragma unroll
    for (int j = 0; j < JB; ++j) {
        const float bv = bias[ccol + j * 32];
#pragma unroll
        for (int i = 0; i < 4; ++i) {
#pragma unroll
            for (int r = 0; r < 16; ++r) {
                const int row = crow + i * 32 + (r & 3) + ((r >> 2) << 3) +
                                (g32 << 2);
                C[(size_t)row * N + (ccol + j * 32)] = acc[i][j][r] + bv;
            }
        }
    }
#undef STAGE
#undef READ_A32
#undef READ_B32
#undef MFMA8
#undef BARF
#undef LGK0
#undef VMDRAIN
}

// ---------------------------------------------------------------------------
// Fallback 128x128 GEMM (round-5 proven) for small-ws modes.
// MODE 1: A f32 reg-staged, B via gload_lds. MODE 2: A f32, B dequant in-kernel.
// ---------------------------------------------------------------------------
template<int MODE>
__global__ __launch_bounds__(256, 2)
void wq_gemm(const float* __restrict__ Af,
             const unsigned short* __restrict__ Wt,
             const int* __restrict__ qweight,
             const int* __restrict__ qzeros,
             const float* __restrict__ scales,
             const float* __restrict__ bias,
             float* __restrict__ C,
             int M, int N, int K, int G)
{
    __shared__ __align__(16) unsigned short As[128][64];
    __shared__ __align__(16) unsigned short Bs[128][64];

    const int tid  = threadIdx.x;
    const int lane = tid & 63;
    const int wid  = tid >> 6;
    const int wr   = wid >> 1;
    const int wc   = wid & 1;
    const int nbx = N / 128;
    int wg = blockIdx.x;
    const int nwg = gridDim.x;
    if ((nwg & 7) == 0) wg = (wg & 7) * (nwg >> 3) + (wg >> 3);
    const int n0 = (wg % nbx) * 128;
    const int m0 = (wg / nbx) * 128;
    const int NP = N >> 3;

    f32x4 acc[4][4] = {};
    const int srow = tid >> 3;
    const int scol = (tid & 7) * 8;
    const float*          Afp = Af + (size_t)(m0 + srow) * K + scol;
    const unsigned short* Bbp = Wt + (size_t)(n0 + srow) * K + scol;
    const int f_kl = (tid & 15) * 4;
    const int f_np = tid >> 4;
    const int fr = lane & 15;
    const int fk = (lane >> 4) * 8;

    for (int kt = 0; kt < K; kt += 64) {
        f32x4 alo[4], ahi[4];
#pragma unroll
        for (int i = 0; i < 4; ++i) {
            alo[i] = *(const f32x4*)(Afp + (size_t)(i * 32) * K + kt);
            ahi[i] = *(const f32x4*)(Afp + (size_t)(i * 32) * K + kt + 4);
        }
#pragma unroll
        for (int i = 0; i < 4; ++i) {
            union { bf16x8 v; unsigned short u[8]; } pk;
#pragma unroll
            for (int e = 0; e < 4; ++e) {
                pk.u[e]     = f2bf(alo[i][e]);
                pk.u[e + 4] = f2bf(ahi[i][e]);
            }
            *(bf16x8*)&As[srow + i * 32][scol] = pk.v;
        }
        if constexpr (MODE == 1) {
#pragma unroll
            for (int i = 0; i < 4; ++i)
                gload_lds16(Bbp + (size_t)(i * 32) * K + kt, &Bs[srow + i * 32][scol]);
        } else {
            const int g  = kt / G;
            const int np = (n0 >> 3) + f_np;
            const int p0 = qweight[(size_t)(kt + f_kl + 0) * NP + np];
            const int p1 = qweight[(size_t)(kt + f_kl + 1) * NP + np];
            const int p2 = qweight[(size_t)(kt + f_kl + 2) * NP + np];
            const int p3 = qweight[(size_t)(kt + f_kl + 3) * NP + np];
            const int zp = qzeros[(size_t)g * NP + np];
            const float* sc = scales + (size_t)g * N + (size_t)np * 8;
#pragma unroll
            for (int j = 0; j < 8; ++j) {
                const int sh = 4 * ((j >> 1) + ((j & 1) << 2));
                const float s = sc[j];
                const float c = -(float)((zp >> sh) & 0xF) * s;
                const int row = f_np * 8 + j;
                Bs[row][f_kl + 0] = f2bf(fmaf((float)((p0 >> sh) & 0xF), s, c));
                Bs[row][f_kl + 1] = f2bf(fmaf((float)((p1 >> sh) & 0xF), s, c));
                Bs[row][f_kl + 2] = f2bf(fmaf((float)((p2 >> sh) & 0xF), s, c));
                Bs[row][f_kl + 3] = f2bf(fmaf((float)((p3 >> sh) & 0xF), s, c));
            }
        }
        __syncthreads();
#pragma unroll
        for (int kk = 0; kk < 64; kk += 32) {
            bf16x8 a[4], b[4];
#pragma unroll
            for (int i = 0; i < 4; ++i)
                a[i] = *(const bf16x8*)&As[wr * 64 + i * 16 + fr][kk + fk];
#pragma unroll
            for (int j = 0; j < 4; ++j)
                b[j] = *(const bf16x8*)&Bs[wc * 64 + j * 16 + fr][kk + fk];
#pragma unroll
            for (int i = 0; i < 4; ++i)
#pragma unroll
                for (int j = 0; j < 4; ++j)
                    acc[i][j] = __builtin_amdgcn_mfma_f32_16x16x32_bf16(
                        a[i], b[j], acc[i][j], 0, 0, 0);
        }
        __syncthreads();
    }
    const int fq = lane >> 4;
#pragma unroll
    for (int j = 0; j < 4; ++j) {
        const int n  = n0 + wc * 64 + j * 16 + fr;
        const float bv2 = bias[n];
#pragma unroll
        for (int i = 0; i < 4; ++i) {
            const int mr = m0 + wr * 64 + i * 16 + fq * 4;
#pragma unroll
            for (int r = 0; r < 4; ++r)
                C[(size_t)(mr + r) * N + n] = acc[i][j][r] + bv2;
        }
    }
}

extern "C" void kernel_launch(void* const* d_in, const int* in_sizes, int n_in,
                              void* d_out, int out_size, void* d_ws, size_t ws_size,
                              hipStream_t stream) {
    const float* x        = (const float*)d_in[0];
    const int*   qweight  = (const int*)d_in[1];
    const int*   qzeros   = (const int*)d_in[2];
    const float* scales   = (const float*)d_in[3];
    const float* bias     = (const float*)d_in[4];
    float*       out      = (float*)d_out;

    const int N  = in_sizes[4];              // 11008
    const int NP = N / 8;                    // 1376
    const int K  = in_sizes[1] / NP;         // 4096
    const int M  = in_sizes[0] / K;          // 8192
    const int n_groups = in_sizes[3] / N;    // 32
    const int G  = K / n_groups;             // 128

    const size_t wt_bytes = (size_t)N * (size_t)K * 2;   // 90.2 MB
    const size_t xb_bytes = (size_t)M * (size_t)K * 2;   // 67.1 MB
    dim3 dq_grid(K / 256, NP);

    const int mb  = M / 256;                 // 32 m-panels
    const int nbt = N / 256;                 // 43 n-panels
    const int nwg256 = mb * nbt;             // 1376

    if (ws_size >= wt_bytes + xb_bytes && (M % 256) == 0 && (N % 256) == 0 &&
        (K % 128) == 0 && (nwg256 & 7) == 0) {
        unsigned short* Wt = (unsigned short*)d_ws;
        unsigned short* xb = (unsigned short*)((char*)d_ws + wt_bytes);

        // R3: pick tail panel count t so main grid = mb*(nbt-t) is an exact
        // multiple of 256 (full rounds); tail = t 256-wide panels done as
        // 2t 128-wide strips (disjoint outputs, short final round).
        int t = -1;
        for (int c = 0; c <= 7 && c < nbt; ++c)
            if ((mb * (nbt - c)) % 256 == 0) { t = c; break; }

        wq_cvt<<<(int)((size_t)M * K / 8 / 256), 256, 0, stream>>>(x, xb);
        wq_dequant<<<dq_grid, 256, 0, stream>>>(qweight, qzeros, scales, Wt, K, NP, G, N);

        if (t > 0) {
            const int main_pan = nbt - t;
            const int main_wg  = mb * main_pan;      // 1280, exact rounds
            wq_gemm256<256, 0><<<main_wg, 512, 0, stream>>>(
                xb, Wt, bias, out, M, N, K, main_pan, 0);
            wq_gemm256<128, 1><<<mb * t * 2, 512, 0, stream>>>(
                xb, Wt, bias, out, M, N, K, 0, main_pan * 256);
        } else {
            // t==0 (already aligned) or no clean split: single grid.
            wq_gemm256<256, 0><<<nwg256, 512, 0, stream>>>(
                xb, Wt, bias, out, M, N, K, nbt, 0);
        }
    } else if (ws_size >= wt_bytes) {
        unsigned short* Wt = (unsigned short*)d_ws;
        const int nwg = (N / 128) * (M / 128);
        wq_dequant<<<dq_grid, 256, 0, stream>>>(qweight, qzeros, scales, Wt, K, NP, G, N);
        wq_gemm<1><<<nwg, 256, 0, stream>>>(x, Wt, qweight, qzeros, scales, bias, out, M, N, K, G);
    } else {
        const int nwg = (N / 128) * (M / 128);
        wq_gemm<2><<<nwg, 256, 0, stream>>>(x, nullptr, qweight, qzeros, scales, bias, out, M, N, K, G);
    }
}

// Round 6
// 695.092 us; speedup vs baseline: 1.0801x; 1.0801x over previous
//
#include <hip/hip_runtime.h>
#include <hip/hip_bf16.h>
#include <stdint.h>

typedef __attribute__((ext_vector_type(4))) float f32x4;
typedef __attribute__((ext_vector_type(8))) short bf16x8;

__device__ __forceinline__ unsigned short f2bf(float f) {
    __hip_bfloat16 h = __float2bfloat16(f);
    return *reinterpret_cast<unsigned short*>(&h);
}

__device__ __forceinline__ void gload_lds16(const void* g, void* l) {
    __builtin_amdgcn_global_load_lds(
        (const __attribute__((address_space(1))) void*)g,
        (__attribute__((address_space(3))) void*)l, 16, 0, 0);
}

// Logical-tile -> (m0,n0): XCD round-robin with n-major order inside each
// XCD's contiguous chunk (R1 L2-locality fix, verified: FETCH 1.56->0.56GB).
__device__ __forceinline__ void tile_map(int logical, int nlog, int nbx,
                                         int& m0, int& n0)
{
    const int per = nlog >> 3;
    const int xcd = logical & 7;
    const int l   = logical >> 3;
    const int mrows = per / nbx;
    if (mrows * nbx == per) {
        const int nj = l / mrows;
        const int mi = l - nj * mrows;
        m0 = (xcd * mrows + mi) * 256;
        n0 = nj * 256;
    } else {
        const int wg = xcd * per + l;
        m0 = (wg / nbx) * 256;
        n0 = (wg % nbx) * 256;
    }
}

// ---------------------------------------------------------------------------
// R6 merged prep: one dispatch covers both passes (saves launch gaps).
//   blocks [0, cvt_blocks):            x f32 -> xb bf16 (8 elems/thread)
//   blocks [cvt_blocks, +dq_blocks):   AWQ int4 -> Wt[N][K] bf16 transposed
// inv = [0,4,1,5,2,6,3,7] => shift = 4*((j>>1) + 4*(j&1)).
// ---------------------------------------------------------------------------
__global__ __launch_bounds__(256)
void wq_prep(const float* __restrict__ x, unsigned short* __restrict__ xb,
             int cvt_blocks,
             const int* __restrict__ qweight, const int* __restrict__ qzeros,
             const float* __restrict__ scales, unsigned short* __restrict__ Wt,
             int K, int NP, int G, int N)
{
    if ((int)blockIdx.x < cvt_blocks) {
        const size_t i = (size_t)blockIdx.x * 256 + threadIdx.x;
        const f32x4 lo = ((const f32x4*)x)[2 * i];
        const f32x4 hi = ((const f32x4*)x)[2 * i + 1];
        union { bf16x8 v; unsigned short u[8]; } pk;
#pragma unroll
        for (int e = 0; e < 4; ++e) {
            pk.u[e]     = f2bf(lo[e]);
            pk.u[e + 4] = f2bf(hi[e]);
        }
        ((bf16x8*)xb)[i] = pk.v;
    } else {
        const int b2  = (int)blockIdx.x - cvt_blocks;
        const int kch = K >> 8;                   // K/256 k-chunks
        const int np  = b2 / kch;
        const int k   = (b2 - np * kch) * 256 + threadIdx.x;
        const int g   = k / G;
        const int p   = qweight[(size_t)k * NP + np];
        const int zp  = qzeros[(size_t)g * NP + np];
        const float* sc = scales + (size_t)g * N + (size_t)np * 8;
#pragma unroll
        for (int j = 0; j < 8; ++j) {
            const int sh = 4 * ((j >> 1) + ((j & 1) << 2));
            const float wv = (float)(((p >> sh) & 0xF) - ((zp >> sh) & 0xF)) * sc[j];
            Wt[(size_t)(np * 8 + j) * K + k] = f2bf(wv);
        }
    }
}

// ---------------------------------------------------------------------------
// 256xBN 8-phase GEMM body (m201 structure, T1+T2+T3+T4+T5) — exact R3 body
// (R4 ping-pong and R5 32x32 both reverted: measured regressions; R5 hit
// 6.3e7 LDS bank conflicts with the 32-row fragment read).
// C[M][N] = A[M][K] * Wt[N][K]^T + bias.  A,Wt bf16; C f32.
// 8 waves (2Mx4N), per-wave 128x(BN/4) out = acc[8][BN/64] 16x16 frags, BK=64.
// LDS: A[buf][256][8 gran] @0, B @65536 (BN rows/tile). Swizzle: phys_gran =
// logical_gran ^ (row&7); gload_lds keeps linear dest + pre-swizzled source.
// vmcnt drain only at p3/p7: BN=256 -> vmcnt(4); BN=128 -> vmcnt(2).
// ---------------------------------------------------------------------------
template<int BN, int TMAP>
__device__ __forceinline__
void gemm_body(char* lds,
               const unsigned short* __restrict__ Ah,
               const unsigned short* __restrict__ Wt,
               const float* __restrict__ bias,
               float* __restrict__ C,
               int M, int N, int K, int nbx, int n_base, int bid, int nwg)
{
    constexpr int FB = BN / 64;            // B frags per wave: 4 or 2

    const int tid  = threadIdx.x;
    const int lane = tid & 63;
    const int w    = tid >> 6;
    const int wr   = w >> 2;           // 0..1
    const int wc   = w & 3;            // 0..3

    int m0, n0;
    if constexpr (TMAP == 0) {
        tile_map(bid, nwg, nbx, m0, n0);
    } else {
        const int mb = M / 256;            // blocks per strip
        m0 = (bid % mb) * 256;
        n0 = n_base + (bid / mb) * BN;
    }

    // ---- stage addressing: wave w, issue ii covers LDS slab (ii*8+w)*1KB ----
    const int lrow = lane >> 3;                          // 0..7
    const int lcol = ((lane & 7) ^ (lrow & 7)) * 8;      // pre-swizzled src col
    const unsigned short* Asrc = Ah + (size_t)(m0 + w * 8 + lrow) * K + lcol;
    const unsigned short* Bsrc = Wt + (size_t)(n0 + w * 8 + lrow) * K + lcol;

    // ---- ds-read addressing: per-lane const XOR -> base VGPR + immediates ----
    const int fr = lane & 15;
    const int fq = lane >> 4;
    const int c0 = (fq ^ (fr & 7)) << 4;                 // bytes
    const int rA0 = wr * 16384 + fr * 128 + c0;          // k-slice 0
    const int rA1 = rA0 ^ 64;                            // k-slice 1
    const int rB0 = 65536 + wc * (BN / 4) * 128 + fr * 128 + c0;
    const int rB1 = rB0 ^ 64;

    f32x4 acc[8][FB] = {};

#define STAGE(gsrc, ob, b, h, kt)                                              \
    {                                                                          \
        _Pragma("unroll")                                                      \
        for (int ii = 0; ii < 2; ++ii)                                         \
            gload_lds16(gsrc + (size_t)((h) * 128 + ii * 64) * K + (kt),       \
                        lds + (ob) + (b) * 32768 + (h) * 16384 +               \
                            (ii * 8 + w) * 1024 + lane * 16);                  \
    }
#define READ_A(dst, b, ilo, rbase)                                             \
    {                                                                          \
        _Pragma("unroll")                                                      \
        for (int ii = 0; ii < 4; ++ii)                                         \
            dst[ii] = *(const bf16x8*)(lds + (rbase) + (b) * 32768 +           \
                                       ((ilo) + ii) * 2048);                   \
    }
#define READ_B(dst, b, rbase)                                                  \
    {                                                                          \
        _Pragma("unroll")                                                      \
        for (int jj = 0; jj < FB; ++jj)                                        \
            dst[jj] = *(const bf16x8*)(lds + (rbase) + (b) * 32768 +           \
                                       jj * 2048);                             \
    }
#define MFMA16(ilo, af_, bf_)                                                  \
    {                                                                          \
        __builtin_amdgcn_s_setprio(1);                                         \
        _Pragma("unroll")                                                      \
        for (int ii = 0; ii < 4; ++ii)                                         \
            _Pragma("unroll")                                                  \
            for (int jj = 0; jj < FB; ++jj)                                    \
                acc[(ilo) + ii][jj] = __builtin_amdgcn_mfma_f32_16x16x32_bf16( \
                    af_[ii], bf_[jj], acc[(ilo) + ii][jj], 0, 0, 0);           \
        __builtin_amdgcn_s_setprio(0);                                         \
    }
#define BARF()  { __builtin_amdgcn_s_barrier(); asm volatile("" ::: "memory"); }
#define LGK0()  { asm volatile("s_waitcnt lgkmcnt(0)" ::: "memory");           \
                  __builtin_amdgcn_sched_barrier(0); }
#define VMDRAIN()                                                              \
    {                                                                          \
        if constexpr (BN == 256)                                               \
            asm volatile("s_waitcnt vmcnt(4)" ::: "memory");                   \
        else                                                                   \
            asm volatile("s_waitcnt vmcnt(2)" ::: "memory");                   \
    }

    // ---- prologue: stage tile0 (B,A) + tile1 B; drain to steady state ----
    STAGE(Bsrc, 65536, 0, 0, 0);
    if constexpr (BN == 256) STAGE(Bsrc, 65536, 0, 1, 0);
    STAGE(Asrc, 0,     0, 0, 0);
    STAGE(Asrc, 0,     0, 1, 0);
    STAGE(Bsrc, 65536, 1, 0, 64);
    if constexpr (BN == 256) STAGE(Bsrc, 65536, 1, 1, 64);
    VMDRAIN();
    BARF();

    const int nit = K / 128;
    for (int it = 0; it < nit; ++it) {
        const int kt1 = it * 128 + 64;            // tile 2it+1 A
        const int kt2 = (it * 128 + 128) % K;     // tile 2it+2
        const int kt3 = (it * 128 + 192) % K;     // tile 2it+3 B
        bf16x8 af[4], bf0[FB], bf1[FB];

        // ======== tile 2it (buf 0) ========
        // p0
        READ_A(af, 0, 0, rA0); READ_B(bf0, 0, rB0);
        STAGE(Asrc, 0, 1, 0, kt1);
        BARF(); LGK0();
        MFMA16(0, af, bf0);
        BARF();
        // p1
        READ_A(af, 0, 0, rA1); READ_B(bf1, 0, rB1);
        STAGE(Asrc, 0, 1, 1, kt1);
        BARF(); LGK0();
        MFMA16(0, af, bf1);
        BARF();
        // p2
        READ_A(af, 0, 4, rA0);
        STAGE(Bsrc, 65536, 0, 0, kt2);
        BARF(); LGK0();
        MFMA16(4, af, bf0);
        BARF();
        // p3
        READ_A(af, 0, 4, rA1);
        if constexpr (BN == 256) STAGE(Bsrc, 65536, 0, 1, kt2);
        BARF(); LGK0();
        MFMA16(4, af, bf1);
        VMDRAIN();
        BARF();

        // ======== tile 2it+1 (buf 1) ========
        // p4
        READ_A(af, 1, 0, rA0); READ_B(bf0, 1, rB0);
        STAGE(Asrc, 0, 0, 0, kt2);
        BARF(); LGK0();
        MFMA16(0, af, bf0);
        BARF();
        // p5
        READ_A(af, 1, 0, rA1); READ_B(bf1, 1, rB1);
        STAGE(Asrc, 0, 0, 1, kt2);
        BARF(); LGK0();
        MFMA16(0, af, bf1);
        BARF();
        // p6
        READ_A(af, 1, 4, rA0);
        STAGE(Bsrc, 65536, 1, 0, kt3);
        BARF(); LGK0();
        MFMA16(4, af, bf0);
        BARF();
        // p7
        READ_A(af, 1, 4, rA1);
        if constexpr (BN == 256) STAGE(Bsrc, 65536, 1, 1, kt3);
        BARF(); LGK0();
        MFMA16(4, af, bf1);
        VMDRAIN();
        BARF();
    }

    // ---- epilogue: D col = lane&15, row = (lane>>4)*4 + reg; f32 out ----
    const int crow = m0 + wr * 128 + fq * 4;
    const int ccol = n0 + wc * (BN / 4) + fr;
#pragma unroll
    for (int j = 0; j < FB; ++j) {
        const float bv = bias[ccol + j * 16];
#pragma unroll
        for (int i = 0; i < 8; ++i) {
#pragma unroll
            for (int r = 0; r < 4; ++r)
                C[(size_t)(crow + i * 16 + r) * N + (ccol + j * 16)] =
                    acc[i][j][r] + bv;
        }
    }
#undef STAGE
#undef READ_A
#undef READ_B
#undef MFMA16
#undef BARF
#undef LGK0
#undef VMDRAIN
}

// ---------------------------------------------------------------------------
// R6 merged GEMM dispatch: blocks [0, main_wg) = BN=256 full-round grid;
// blocks [main_wg, end) = BN=128 tail strips (disjoint outputs). Single
// dispatch lets tail blocks fill CUs as the last main round drains, instead
// of serializing behind it (same-stream kernels cannot overlap).
// Branch is block-uniform; LDS declared once here, shared by both bodies.
// ---------------------------------------------------------------------------
__global__ __launch_bounds__(512, 2)
void wq_gemm_all(const unsigned short* __restrict__ Ah,
                 const unsigned short* __restrict__ Wt,
                 const float* __restrict__ bias,
                 float* __restrict__ C,
                 int M, int N, int K, int main_wg, int main_pan)
{
    __shared__ __align__(16) char lds[131072];
    if ((int)blockIdx.x < main_wg) {
        gemm_body<256, 0>(lds, Ah, Wt, bias, C, M, N, K,
                          main_pan, 0, (int)blockIdx.x, main_wg);
    } else {
        gemm_body<128, 1>(lds, Ah, Wt, bias, C, M, N, K,
                          0, main_pan * 256, (int)blockIdx.x - main_wg, 0);
    }
}

// ---------------------------------------------------------------------------
// Fallback 128x128 GEMM (round-5 proven) for small-ws modes.
// MODE 1: A f32 reg-staged, B via gload_lds. MODE 2: A f32, B dequant in-kernel.
// ---------------------------------------------------------------------------
template<int MODE>
__global__ __launch_bounds__(256, 2)
void wq_gemm(const float* __restrict__ Af,
             const unsigned short* __restrict__ Wt,
             const int* __restrict__ qweight,
             const int* __restrict__ qzeros,
             const float* __restrict__ scales,
             const float* __restrict__ bias,
             float* __restrict__ C,
             int M, int N, int K, int G)
{
    __shared__ __align__(16) unsigned short As[128][64];
    __shared__ __align__(16) unsigned short Bs[128][64];

    const int tid  = threadIdx.x;
    const int lane = tid & 63;
    const int wid  = tid >> 6;
    const int wr   = wid >> 1;
    const int wc   = wid & 1;
    const int nbx = N / 128;
    int wg = blockIdx.x;
    const int nwg = gridDim.x;
    if ((nwg & 7) == 0) wg = (wg & 7) * (nwg >> 3) + (wg >> 3);
    const int n0 = (wg % nbx) * 128;
    const int m0 = (wg / nbx) * 128;
    const int NP = N >> 3;

    f32x4 acc[4][4] = {};
    const int srow = tid >> 3;
    const int scol = (tid & 7) * 8;
    const float*          Afp = Af + (size_t)(m0 + srow) * K + scol;
    const unsigned short* Bbp = Wt + (size_t)(n0 + srow) * K + scol;
    const int f_kl = (tid & 15) * 4;
    const int f_np = tid >> 4;
    const int fr = lane & 15;
    const int fk = (lane >> 4) * 8;

    for (int kt = 0; kt < K; kt += 64) {
        f32x4 alo[4], ahi[4];
#pragma unroll
        for (int i = 0; i < 4; ++i) {
            alo[i] = *(const f32x4*)(Afp + (size_t)(i * 32) * K + kt);
            ahi[i] = *(const f32x4*)(Afp + (size_t)(i * 32) * K + kt + 4);
        }
#pragma unroll
        for (int i = 0; i < 4; ++i) {
            union { bf16x8 v; unsigned short u[8]; } pk;
#pragma unroll
            for (int e = 0; e < 4; ++e) {
                pk.u[e]     = f2bf(alo[i][e]);
                pk.u[e + 4] = f2bf(ahi[i][e]);
            }
            *(bf16x8*)&As[srow + i * 32][scol] = pk.v;
        }
        if constexpr (MODE == 1) {
#pragma unroll
            for (int i = 0; i < 4; ++i)
                gload_lds16(Bbp + (size_t)(i * 32) * K + kt, &Bs[srow + i * 32][scol]);
        } else {
            const int g  = kt / G;
            const int np = (n0 >> 3) + f_np;
            const int p0 = qweight[(size_t)(kt + f_kl + 0) * NP + np];
            const int p1 = qweight[(size_t)(kt + f_kl + 1) * NP + np];
            const int p2 = qweight[(size_t)(kt + f_kl + 2) * NP + np];
            const int p3 = qweight[(size_t)(kt + f_kl + 3) * NP + np];
            const int zp = qzeros[(size_t)g * NP + np];
            const float* sc = scales + (size_t)g * N + (size_t)np * 8;
#pragma unroll
            for (int j = 0; j < 8; ++j) {
                const int sh = 4 * ((j >> 1) + ((j & 1) << 2));
                const float s = sc[j];
                const float c = -(float)((zp >> sh) & 0xF) * s;
                const int row = f_np * 8 + j;
                Bs[row][f_kl + 0] = f2bf(fmaf((float)((p0 >> sh) & 0xF), s, c));
                Bs[row][f_kl + 1] = f2bf(fmaf((float)((p1 >> sh) & 0xF), s, c));
                Bs[row][f_kl + 2] = f2bf(fmaf((float)((p2 >> sh) & 0xF), s, c));
                Bs[row][f_kl + 3] = f2bf(fmaf((float)((p3 >> sh) & 0xF), s, c));
            }
        }
        __syncthreads();
#pragma unroll
        for (int kk = 0; kk < 64; kk += 32) {
            bf16x8 a[4], b[4];
#pragma unroll
            for (int i = 0; i < 4; ++i)
                a[i] = *(const bf16x8*)&As[wr * 64 + i * 16 + fr][kk + fk];
#pragma unroll
            for (int j = 0; j < 4; ++j)
                b[j] = *(const bf16x8*)&Bs[wc * 64 + j * 16 + fr][kk + fk];
#pragma unroll
            for (int i = 0; i < 4; ++i)
#pragma unroll
                for (int j = 0; j < 4; ++j)
                    acc[i][j] = __builtin_amdgcn_mfma_f32_16x16x32_bf16(
                        a[i], b[j], acc[i][j], 0, 0, 0);
        }
        __syncthreads();
    }
    const int fq = lane >> 4;
#pragma unroll
    for (int j = 0; j < 4; ++j) {
        const int n  = n0 + wc * 64 + j * 16 + fr;
        const float bv2 = bias[n];
#pragma unroll
        for (int i = 0; i < 4; ++i) {
            const int mr = m0 + wr * 64 + i * 16 + fq * 4;
#pragma unroll
            for (int r = 0; r < 4; ++r)
                C[(size_t)(mr + r) * N + n] = acc[i][j][r] + bv2;
        }
    }
}

extern "C" void kernel_launch(void* const* d_in, const int* in_sizes, int n_in,
                              void* d_out, int out_size, void* d_ws, size_t ws_size,
                              hipStream_t stream) {
    const float* x        = (const float*)d_in[0];
    const int*   qweight  = (const int*)d_in[1];
    const int*   qzeros   = (const int*)d_in[2];
    const float* scales   = (const float*)d_in[3];
    const float* bias     = (const float*)d_in[4];
    float*       out      = (float*)d_out;

    const int N  = in_sizes[4];              // 11008
    const int NP = N / 8;                    // 1376
    const int K  = in_sizes[1] / NP;         // 4096
    const int M  = in_sizes[0] / K;          // 8192
    const int n_groups = in_sizes[3] / N;    // 32
    const int G  = K / n_groups;             // 128

    const size_t wt_bytes = (size_t)N * (size_t)K * 2;   // 90.2 MB
    const size_t xb_bytes = (size_t)M * (size_t)K * 2;   // 67.1 MB

    const int mb  = M / 256;                 // 32 m-panels
    const int nbt = N / 256;                 // 43 n-panels
    const int nwg256 = mb * nbt;             // 1376

    if (ws_size >= wt_bytes + xb_bytes && (M % 256) == 0 && (N % 256) == 0 &&
        (K % 128) == 0 && (K % 256) == 0 && (nwg256 & 7) == 0) {
        unsigned short* Wt = (unsigned short*)d_ws;
        unsigned short* xb = (unsigned short*)((char*)d_ws + wt_bytes);

        // R3 tail split: t n-panels so main grid = mb*(nbt-t) is an exact
        // multiple of 256 (full rounds); tail = 2t BN=128 strips.
        int t = -1;
        for (int c = 0; c <= 7 && c < nbt; ++c)
            if ((mb * (nbt - c)) % 256 == 0) { t = c; break; }

        const int cvt_blocks = (int)((size_t)M * K / 8 / 256);
        const int dq_blocks  = (K / 256) * NP;
        wq_prep<<<cvt_blocks + dq_blocks, 256, 0, stream>>>(
            x, xb, cvt_blocks, qweight, qzeros, scales, Wt, K, NP, G, N);

        if (t > 0) {
            const int main_pan = nbt - t;
            const int main_wg  = mb * main_pan;      // 1280, exact rounds
            const int tail_wg  = mb * t * 2;         // 192 BN=128 strips
            wq_gemm_all<<<main_wg + tail_wg, 512, 0, stream>>>(
                xb, Wt, bias, out, M, N, K, main_wg, main_pan);
        } else {
            wq_gemm_all<<<nwg256, 512, 0, stream>>>(
                xb, Wt, bias, out, M, N, K, nwg256, nbt);
        }
    } else if (ws_size >= wt_bytes) {
        unsigned short* Wt = (unsigned short*)d_ws;
        dim3 dq_grid(K / 256, NP);
        const int nwg = (N / 128) * (M / 128);
        // legacy separate dequant for fallback path
        wq_prep<<<(K / 256) * NP, 256, 0, stream>>>(
            x, nullptr, 0, qweight, qzeros, scales, Wt, K, NP, G, N);
        wq_gemm<1><<<nwg, 256, 0, stream>>>(x, Wt, qweight, qzeros, scales, bias, out, M, N, K, G);
    } else {
        const int nwg = (N / 128) * (M / 128);
        wq_gemm<2><<<nwg, 256, 0, stream>>>(x, nullptr, qweight, qzeros, scales, bias, out, M, N, K, G);
    }
}

// Round 7
// 676.442 us; speedup vs baseline: 1.1098x; 1.0276x over previous
//
#include <hip/hip_runtime.h>
#include <hip/hip_bf16.h>
#include <stdint.h>

typedef __attribute__((ext_vector_type(4))) float f32x4;
typedef __attribute__((ext_vector_type(8))) short bf16x8;

__device__ __forceinline__ unsigned short f2bf(float f) {
    __hip_bfloat16 h = __float2bfloat16(f);
    return *reinterpret_cast<unsigned short*>(&h);
}

__device__ __forceinline__ void gload_lds16(const void* g, void* l) {
    __builtin_amdgcn_global_load_lds(
        (const __attribute__((address_space(1))) void*)g,
        (__attribute__((address_space(3))) void*)l, 16, 0, 0);
}

// Logical-tile -> (m0,n0): XCD round-robin with n-major order inside each
// XCD's contiguous chunk (R1 L2-locality fix, verified: FETCH 1.56->0.56GB).
__device__ __forceinline__ void tile_map(int logical, int nlog, int nbx,
                                         int& m0, int& n0)
{
    const int per = nlog >> 3;
    const int xcd = logical & 7;
    const int l   = logical >> 3;
    const int mrows = per / nbx;
    if (mrows * nbx == per) {
        const int nj = l / mrows;
        const int mi = l - nj * mrows;
        m0 = (xcd * mrows + mi) * 256;
        n0 = nj * 256;
    } else {
        const int wg = xcd * per + l;
        m0 = (wg / nbx) * 256;
        n0 = (wg % nbx) * 256;
    }
}

// ---------------------------------------------------------------------------
// R6 merged prep: one dispatch covers both passes.
// R7: read-once inputs (x, qweight) use non-temporal loads so they do not
// occupy L3 — L3 is reserved for the GEMM working set (xb+Wt = 157MB fits).
//   blocks [0, cvt_blocks):            x f32 -> xb bf16 (8 elems/thread)
//   blocks [cvt_blocks, +dq_blocks):   AWQ int4 -> Wt[N][K] bf16 transposed
// inv = [0,4,1,5,2,6,3,7] => shift = 4*((j>>1) + 4*(j&1)).
// ---------------------------------------------------------------------------
__global__ __launch_bounds__(256)
void wq_prep(const float* __restrict__ x, unsigned short* __restrict__ xb,
             int cvt_blocks,
             const int* __restrict__ qweight, const int* __restrict__ qzeros,
             const float* __restrict__ scales, unsigned short* __restrict__ Wt,
             int K, int NP, int G, int N)
{
    if ((int)blockIdx.x < cvt_blocks) {
        const size_t i = (size_t)blockIdx.x * 256 + threadIdx.x;
        const f32x4 lo = __builtin_nontemporal_load(&((const f32x4*)x)[2 * i]);
        const f32x4 hi = __builtin_nontemporal_load(&((const f32x4*)x)[2 * i + 1]);
        union { bf16x8 v; unsigned short u[8]; } pk;
#pragma unroll
        for (int e = 0; e < 4; ++e) {
            pk.u[e]     = f2bf(lo[e]);
            pk.u[e + 4] = f2bf(hi[e]);
        }
        ((bf16x8*)xb)[i] = pk.v;
    } else {
        const int b2  = (int)blockIdx.x - cvt_blocks;
        const int kch = K >> 8;                   // K/256 k-chunks
        const int np  = b2 / kch;
        const int k   = (b2 - np * kch) * 256 + threadIdx.x;
        const int g   = k / G;
        const int p   = __builtin_nontemporal_load(&qweight[(size_t)k * NP + np]);
        const int zp  = qzeros[(size_t)g * NP + np];
        const float* sc = scales + (size_t)g * N + (size_t)np * 8;
#pragma unroll
        for (int j = 0; j < 8; ++j) {
            const int sh = 4 * ((j >> 1) + ((j & 1) << 2));
            const float wv = (float)(((p >> sh) & 0xF) - ((zp >> sh) & 0xF)) * sc[j];
            Wt[(size_t)(np * 8 + j) * K + k] = f2bf(wv);
        }
    }
}

// ---------------------------------------------------------------------------
// 256xBN 8-phase GEMM body (m201 structure, T1+T2+T3+T4+T5) — R3 body.
// (R4 ping-pong and R5 32x32 reverted: measured regressions.)
// C[M][N] = A[M][K] * Wt[N][K]^T + bias.  A,Wt bf16; C f32.
// 8 waves (2Mx4N), per-wave 128x(BN/4) out = acc[8][BN/64] 16x16 frags, BK=64.
// LDS: A[buf][256][8 gran] @0, B @65536 (BN rows/tile). Swizzle: phys_gran =
// logical_gran ^ (row&7); gload_lds keeps linear dest + pre-swizzled source.
// vmcnt drain only at p3/p7: BN=256 -> vmcnt(4); BN=128 -> vmcnt(2).
// R7: C stores are NON-TEMPORAL. C is written once and never re-read; without
// nt, 430MB of C traffic streams through L2/L3 and evicts the 157MB input
// working set every round (FETCH 564MB vs 157MB compulsory) — the resulting
// HBM-latency staging misses are the p3/p7 stall. nt keeps inputs L3-resident.
// ---------------------------------------------------------------------------
template<int BN, int TMAP>
__device__ __forceinline__
void gemm_body(char* lds,
               const unsigned short* __restrict__ Ah,
               const unsigned short* __restrict__ Wt,
               const float* __restrict__ bias,
               float* __restrict__ C,
               int M, int N, int K, int nbx, int n_base, int bid, int nwg)
{
    constexpr int FB = BN / 64;            // B frags per wave: 4 or 2

    const int tid  = threadIdx.x;
    const int lane = tid & 63;
    const int w    = tid >> 6;
    const int wr   = w >> 2;           // 0..1
    const int wc   = w & 3;            // 0..3

    int m0, n0;
    if constexpr (TMAP == 0) {
        tile_map(bid, nwg, nbx, m0, n0);
    } else {
        const int mb = M / 256;            // blocks per strip
        m0 = (bid % mb) * 256;
        n0 = n_base + (bid / mb) * BN;
    }

    // ---- stage addressing: wave w, issue ii covers LDS slab (ii*8+w)*1KB ----
    const int lrow = lane >> 3;                          // 0..7
    const int lcol = ((lane & 7) ^ (lrow & 7)) * 8;      // pre-swizzled src col
    const unsigned short* Asrc = Ah + (size_t)(m0 + w * 8 + lrow) * K + lcol;
    const unsigned short* Bsrc = Wt + (size_t)(n0 + w * 8 + lrow) * K + lcol;

    // ---- ds-read addressing: per-lane const XOR -> base VGPR + immediates ----
    const int fr = lane & 15;
    const int fq = lane >> 4;
    const int c0 = (fq ^ (fr & 7)) << 4;                 // bytes
    const int rA0 = wr * 16384 + fr * 128 + c0;          // k-slice 0
    const int rA1 = rA0 ^ 64;                            // k-slice 1
    const int rB0 = 65536 + wc * (BN / 4) * 128 + fr * 128 + c0;
    const int rB1 = rB0 ^ 64;

    f32x4 acc[8][FB] = {};

#define STAGE(gsrc, ob, b, h, kt)                                              \
    {                                                                          \
        _Pragma("unroll")                                                      \
        for (int ii = 0; ii < 2; ++ii)                                         \
            gload_lds16(gsrc + (size_t)((h) * 128 + ii * 64) * K + (kt),       \
                        lds + (ob) + (b) * 32768 + (h) * 16384 +               \
                            (ii * 8 + w) * 1024 + lane * 16);                  \
    }
#define READ_A(dst, b, ilo, rbase)                                             \
    {                                                                          \
        _Pragma("unroll")                                                      \
        for (int ii = 0; ii < 4; ++ii)                                         \
            dst[ii] = *(const bf16x8*)(lds + (rbase) + (b) * 32768 +           \
                                       ((ilo) + ii) * 2048);                   \
    }
#define READ_B(dst, b, rbase)                                                  \
    {                                                                          \
        _Pragma("unroll")                                                      \
        for (int jj = 0; jj < FB; ++jj)                                        \
            dst[jj] = *(const bf16x8*)(lds + (rbase) + (b) * 32768 +           \
                                       jj * 2048);                             \
    }
#define MFMA16(ilo, af_, bf_)                                                  \
    {                                                                          \
        __builtin_amdgcn_s_setprio(1);                                         \
        _Pragma("unroll")                                                      \
        for (int ii = 0; ii < 4; ++ii)                                         \
            _Pragma("unroll")                                                  \
            for (int jj = 0; jj < FB; ++jj)                                    \
                acc[(ilo) + ii][jj] = __builtin_amdgcn_mfma_f32_16x16x32_bf16( \
                    af_[ii], bf_[jj], acc[(ilo) + ii][jj], 0, 0, 0);           \
        __builtin_amdgcn_s_setprio(0);                                         \
    }
#define BARF()  { __builtin_amdgcn_s_barrier(); asm volatile("" ::: "memory"); }
#define LGK0()  { asm volatile("s_waitcnt lgkmcnt(0)" ::: "memory");           \
                  __builtin_amdgcn_sched_barrier(0); }
#define VMDRAIN()                                                              \
    {                                                                          \
        if constexpr (BN == 256)                                               \
            asm volatile("s_waitcnt vmcnt(4)" ::: "memory");                   \
        else                                                                   \
            asm volatile("s_waitcnt vmcnt(2)" ::: "memory");                   \
    }

    // ---- prologue: stage tile0 (B,A) + tile1 B; drain to steady state ----
    STAGE(Bsrc, 65536, 0, 0, 0);
    if constexpr (BN == 256) STAGE(Bsrc, 65536, 0, 1, 0);
    STAGE(Asrc, 0,     0, 0, 0);
    STAGE(Asrc, 0,     0, 1, 0);
    STAGE(Bsrc, 65536, 1, 0, 64);
    if constexpr (BN == 256) STAGE(Bsrc, 65536, 1, 1, 64);
    VMDRAIN();
    BARF();

    const int nit = K / 128;
    for (int it = 0; it < nit; ++it) {
        const int kt1 = it * 128 + 64;            // tile 2it+1 A
        const int kt2 = (it * 128 + 128) % K;     // tile 2it+2
        const int kt3 = (it * 128 + 192) % K;     // tile 2it+3 B
        bf16x8 af[4], bf0[FB], bf1[FB];

        // ======== tile 2it (buf 0) ========
        // p0
        READ_A(af, 0, 0, rA0); READ_B(bf0, 0, rB0);
        STAGE(Asrc, 0, 1, 0, kt1);
        BARF(); LGK0();
        MFMA16(0, af, bf0);
        BARF();
        // p1
        READ_A(af, 0, 0, rA1); READ_B(bf1, 0, rB1);
        STAGE(Asrc, 0, 1, 1, kt1);
        BARF(); LGK0();
        MFMA16(0, af, bf1);
        BARF();
        // p2
        READ_A(af, 0, 4, rA0);
        STAGE(Bsrc, 65536, 0, 0, kt2);
        BARF(); LGK0();
        MFMA16(4, af, bf0);
        BARF();
        // p3
        READ_A(af, 0, 4, rA1);
        if constexpr (BN == 256) STAGE(Bsrc, 65536, 0, 1, kt2);
        BARF(); LGK0();
        MFMA16(4, af, bf1);
        VMDRAIN();
        BARF();

        // ======== tile 2it+1 (buf 1) ========
        // p4
        READ_A(af, 1, 0, rA0); READ_B(bf0, 1, rB0);
        STAGE(Asrc, 0, 0, 0, kt2);
        BARF(); LGK0();
        MFMA16(0, af, bf0);
        BARF();
        // p5
        READ_A(af, 1, 0, rA1); READ_B(bf1, 1, rB1);
        STAGE(Asrc, 0, 0, 1, kt2);
        BARF(); LGK0();
        MFMA16(0, af, bf1);
        BARF();
        // p6
        READ_A(af, 1, 4, rA0);
        STAGE(Bsrc, 65536, 1, 0, kt3);
        BARF(); LGK0();
        MFMA16(4, af, bf0);
        BARF();
        // p7
        READ_A(af, 1, 4, rA1);
        if constexpr (BN == 256) STAGE(Bsrc, 65536, 1, 1, kt3);
        BARF(); LGK0();
        MFMA16(4, af, bf1);
        VMDRAIN();
        BARF();
    }

    // ---- epilogue: D col = lane&15, row = (lane>>4)*4 + reg; f32 out ----
    // R7: non-temporal stores — C must not evict the L3 input working set.
    const int crow = m0 + wr * 128 + fq * 4;
    const int ccol = n0 + wc * (BN / 4) + fr;
#pragma unroll
    for (int j = 0; j < FB; ++j) {
        const float bv = bias[ccol + j * 16];
#pragma unroll
        for (int i = 0; i < 8; ++i) {
#pragma unroll
            for (int r = 0; r < 4; ++r)
                __builtin_nontemporal_store(
                    acc[i][j][r] + bv,
                    &C[(size_t)(crow + i * 16 + r) * N + (ccol + j * 16)]);
        }
    }
#undef STAGE
#undef READ_A
#undef READ_B
#undef MFMA16
#undef BARF
#undef LGK0
#undef VMDRAIN
}

// ---------------------------------------------------------------------------
// R6 merged GEMM dispatch: blocks [0, main_wg) = BN=256 full-round grid;
// blocks [main_wg, end) = BN=128 tail strips (disjoint outputs).
// ---------------------------------------------------------------------------
__global__ __launch_bounds__(512, 2)
void wq_gemm_all(const unsigned short* __restrict__ Ah,
                 const unsigned short* __restrict__ Wt,
                 const float* __restrict__ bias,
                 float* __restrict__ C,
                 int M, int N, int K, int main_wg, int main_pan)
{
    __shared__ __align__(16) char lds[131072];
    if ((int)blockIdx.x < main_wg) {
        gemm_body<256, 0>(lds, Ah, Wt, bias, C, M, N, K,
                          main_pan, 0, (int)blockIdx.x, main_wg);
    } else {
        gemm_body<128, 1>(lds, Ah, Wt, bias, C, M, N, K,
                          0, main_pan * 256, (int)blockIdx.x - main_wg, 0);
    }
}

// ---------------------------------------------------------------------------
// Fallback 128x128 GEMM (round-5 proven) for small-ws modes.
// MODE 1: A f32 reg-staged, B via gload_lds. MODE 2: A f32, B dequant in-kernel.
// ---------------------------------------------------------------------------
template<int MODE>
__global__ __launch_bounds__(256, 2)
void wq_gemm(const float* __restrict__ Af,
             const unsigned short* __restrict__ Wt,
             const int* __restrict__ qweight,
             const int* __restrict__ qzeros,
             const float* __restrict__ scales,
             const float* __restrict__ bias,
             float* __restrict__ C,
             int M, int N, int K, int G)
{
    __shared__ __align__(16) unsigned short As[128][64];
    __shared__ __align__(16) unsigned short Bs[128][64];

    const int tid  = threadIdx.x;
    const int lane = tid & 63;
    const int wid  = tid >> 6;
    const int wr   = wid >> 1;
    const int wc   = wid & 1;
    const int nbx = N / 128;
    int wg = blockIdx.x;
    const int nwg = gridDim.x;
    if ((nwg & 7) == 0) wg = (wg & 7) * (nwg >> 3) + (wg >> 3);
    const int n0 = (wg % nbx) * 128;
    const int m0 = (wg / nbx) * 128;
    const int NP = N >> 3;

    f32x4 acc[4][4] = {};
    const int srow = tid >> 3;
    const int scol = (tid & 7) * 8;
    const float*          Afp = Af + (size_t)(m0 + srow) * K + scol;
    const unsigned short* Bbp = Wt + (size_t)(n0 + srow) * K + scol;
    const int f_kl = (tid & 15) * 4;
    const int f_np = tid >> 4;
    const int fr = lane & 15;
    const int fk = (lane >> 4) * 8;

    for (int kt = 0; kt < K; kt += 64) {
        f32x4 alo[4], ahi[4];
#pragma unroll
        for (int i = 0; i < 4; ++i) {
            alo[i] = *(const f32x4*)(Afp + (size_t)(i * 32) * K + kt);
            ahi[i] = *(const f32x4*)(Afp + (size_t)(i * 32) * K + kt + 4);
        }
#pragma unroll
        for (int i = 0; i < 4; ++i) {
            union { bf16x8 v; unsigned short u[8]; } pk;
#pragma unroll
            for (int e = 0; e < 4; ++e) {
                pk.u[e]     = f2bf(alo[i][e]);
                pk.u[e + 4] = f2bf(ahi[i][e]);
            }
            *(bf16x8*)&As[srow + i * 32][scol] = pk.v;
        }
        if constexpr (MODE == 1) {
#pragma unroll
            for (int i = 0; i < 4; ++i)
                gload_lds16(Bbp + (size_t)(i * 32) * K + kt, &Bs[srow + i * 32][scol]);
        } else {
            const int g  = kt / G;
            const int np = (n0 >> 3) + f_np;
            const int p0 = qweight[(size_t)(kt + f_kl + 0) * NP + np];
            const int p1 = qweight[(size_t)(kt + f_kl + 1) * NP + np];
            const int p2 = qweight[(size_t)(kt + f_kl + 2) * NP + np];
            const int p3 = qweight[(size_t)(kt + f_kl + 3) * NP + np];
            const int zp = qzeros[(size_t)g * NP + np];
            const float* sc = scales + (size_t)g * N + (size_t)np * 8;
#pragma unroll
            for (int j = 0; j < 8; ++j) {
                const int sh = 4 * ((j >> 1) + ((j & 1) << 2));
                const float s = sc[j];
                const float c = -(float)((zp >> sh) & 0xF) * s;
                const int row = f_np * 8 + j;
                Bs[row][f_kl + 0] = f2bf(fmaf((float)((p0 >> sh) & 0xF), s, c));
                Bs[row][f_kl + 1] = f2bf(fmaf((float)((p1 >> sh) & 0xF), s, c));
                Bs[row][f_kl + 2] = f2bf(fmaf((float)((p2 >> sh) & 0xF), s, c));
                Bs[row][f_kl + 3] = f2bf(fmaf((float)((p3 >> sh) & 0xF), s, c));
            }
        }
        __syncthreads();
#pragma unroll
        for (int kk = 0; kk < 64; kk += 32) {
            bf16x8 a[4], b[4];
#pragma unroll
            for (int i = 0; i < 4; ++i)
                a[i] = *(const bf16x8*)&As[wr * 64 + i * 16 + fr][kk + fk];
#pragma unroll
            for (int j = 0; j < 4; ++j)
                b[j] = *(const bf16x8*)&Bs[wc * 64 + j * 16 + fr][kk + fk];
#pragma unroll
            for (int i = 0; i < 4; ++i)
#pragma unroll
                for (int j = 0; j < 4; ++j)
                    acc[i][j] = __builtin_amdgcn_mfma_f32_16x16x32_bf16(
                        a[i], b[j], acc[i][j], 0, 0, 0);
        }
        __syncthreads();
    }
    const int fq = lane >> 4;
#pragma unroll
    for (int j = 0; j < 4; ++j) {
        const int n  = n0 + wc * 64 + j * 16 + fr;
        const float bv2 = bias[n];
#pragma unroll
        for (int i = 0; i < 4; ++i) {
            const int mr = m0 + wr * 64 + i * 16 + fq * 4;
#pragma unroll
            for (int r = 0; r < 4; ++r)
                __builtin_nontemporal_store(acc[i][j][r] + bv2,
                                            &C[(size_t)(mr + r) * N + n]);
        }
    }
}

extern "C" void kernel_launch(void* const* d_in, const int* in_sizes, int n_in,
                              void* d_out, int out_size, void* d_ws, size_t ws_size,
                              hipStream_t stream) {
    const float* x        = (const float*)d_in[0];
    const int*   qweight  = (const int*)d_in[1];
    const int*   qzeros   = (const int*)d_in[2];
    const float* scales   = (const float*)d_in[3];
    const float* bias     = (const float*)d_in[4];
    float*       out      = (float*)d_out;

    const int N  = in_sizes[4];              // 11008
    const int NP = N / 8;                    // 1376
    const int K  = in_sizes[1] / NP;         // 4096
    const int M  = in_sizes[0] / K;          // 8192
    const int n_groups = in_sizes[3] / N;    // 32
    const int G  = K / n_groups;             // 128

    const size_t wt_bytes = (size_t)N * (size_t)K * 2;   // 90.2 MB
    const size_t xb_bytes = (size_t)M * (size_t)K * 2;   // 67.1 MB

    const int mb  = M / 256;                 // 32 m-panels
    const int nbt = N / 256;                 // 43 n-panels
    const int nwg256 = mb * nbt;             // 1376

    if (ws_size >= wt_bytes + xb_bytes && (M % 256) == 0 && (N % 256) == 0 &&
        (K % 128) == 0 && (K % 256) == 0 && (nwg256 & 7) == 0) {
        unsigned short* Wt = (unsigned short*)d_ws;
        unsigned short* xb = (unsigned short*)((char*)d_ws + wt_bytes);

        // R3 tail split: t n-panels so main grid = mb*(nbt-t) is an exact
        // multiple of 256 (full rounds); tail = 2t BN=128 strips.
        int t = -1;
        for (int c = 0; c <= 7 && c < nbt; ++c)
            if ((mb * (nbt - c)) % 256 == 0) { t = c; break; }

        const int cvt_blocks = (int)((size_t)M * K / 8 / 256);
        const int dq_blocks  = (K / 256) * NP;
        wq_prep<<<cvt_blocks + dq_blocks, 256, 0, stream>>>(
            x, xb, cvt_blocks, qweight, qzeros, scales, Wt, K, NP, G, N);

        if (t > 0) {
            const int main_pan = nbt - t;
            const int main_wg  = mb * main_pan;      // 1280, exact rounds
            const int tail_wg  = mb * t * 2;         // 192 BN=128 strips
            wq_gemm_all<<<main_wg + tail_wg, 512, 0, stream>>>(
                xb, Wt, bias, out, M, N, K, main_wg, main_pan);
        } else {
            wq_gemm_all<<<nwg256, 512, 0, stream>>>(
                xb, Wt, bias, out, M, N, K, nwg256, nbt);
        }
    } else if (ws_size >= wt_bytes) {
        unsigned short* Wt = (unsigned short*)d_ws;
        const int nwg = (N / 128) * (M / 128);
        wq_prep<<<(K / 256) * NP, 256, 0, stream>>>(
            x, nullptr, 0, qweight, qzeros, scales, Wt, K, NP, G, N);
        wq_gemm<1><<<nwg, 256, 0, stream>>>(x, Wt, qweight, qzeros, scales, bias, out, M, N, K, G);
    } else {
        const int nwg = (N / 128) * (M / 128);
        wq_gemm<2><<<nwg, 256, 0, stream>>>(x, nullptr, qweight, qzeros, scales, bias, out, M, N, K, G);
    }
}